// Round 1
// baseline (205.011 us; speedup 1.0000x reference)
//
#include <hip/hip_runtime.h>
#include <stdint.h>
#include <stddef.h>

typedef unsigned short ushort_t;
typedef __attribute__((ext_vector_type(8))) short short8;
typedef __attribute__((ext_vector_type(4))) short short4v;
typedef __attribute__((ext_vector_type(4))) float f32x4;
typedef __attribute__((ext_vector_type(4))) unsigned int uint4v;

#define GL2LDS(gsrc, ldst) \
  __builtin_amdgcn_global_load_lds((const __attribute__((address_space(1))) void*)(gsrc), \
                                   (__attribute__((address_space(3))) void*)(ldst), 16, 0, 0)

__device__ __forceinline__ float bf2f(ushort_t u) {
  union { unsigned int i; float f; } v; v.i = ((unsigned int)u) << 16; return v.f;
}
__device__ __forceinline__ ushort_t f2bf(float f) {
  unsigned int u = __builtin_bit_cast(unsigned int, f);
  unsigned int r = (u + 0x7fffu + ((u >> 16) & 1u)) >> 16;
  return (ushort_t)r;
}

// ---------------------------------------------------------------------------
// K0: e4wT[o][c] = bf16(M[c][o]), M[c][o] = e4w_flat[c*128+o] for c<16384,
//     e4_b[(c-16384)*128+o] for c in [16384,16512). Row stride 16512.
// ---------------------------------------------------------------------------
__global__ void k_prep(const float* __restrict__ e4w, const float* __restrict__ e4b,
                       ushort_t* __restrict__ e4wT) {
  __shared__ float t[128][65];
  int c0 = blockIdx.x * 64;
  int tid = threadIdx.x;
  for (int it = 0; it < 32; ++it) {
    int idx = it * 256 + tid;
    int cc = idx >> 7, oo = idx & 127;
    int c = c0 + cc;
    float v = (c < 16384) ? e4w[(size_t)c * 128 + oo] : e4b[(size_t)(c - 16384) * 128 + oo];
    t[oo][cc] = v;
  }
  __syncthreads();
  for (int it = 0; it < 32; ++it) {
    int idx = it * 256 + tid;
    int oo = idx >> 6, cc = idx & 63;
    e4wT[(size_t)oo * 16512 + c0 + cc] = f2bf(t[oo][cc]);
  }
}

// ---------------------------------------------------------------------------
// K1: node MLP  h = relu(x@p1+b1)@p2+b2 -> bf16 [4096][128]
// ---------------------------------------------------------------------------
__global__ void k_node(const float* __restrict__ x, const float* __restrict__ p1w,
                       const float* __restrict__ p1b, const float* __restrict__ p2w,
                       const float* __restrict__ p2b, ushort_t* __restrict__ h_node) {
  __shared__ float xs[8][12];
  __shared__ float t1[8][128];
  int n0 = blockIdx.x * 8, tid = threadIdx.x;
  if (tid < 88) { int n = tid / 11, j = tid % 11; xs[n][j] = x[(size_t)(n0 + n) * 11 + j]; }
  __syncthreads();
  for (int it = 0; it < 4; ++it) {
    int p = it * 256 + tid;
    int n = p >> 7, o = p & 127;
    float a = p1b[o];
#pragma unroll
    for (int j = 0; j < 11; ++j) a += xs[n][j] * p1w[j * 128 + o];
    t1[n][o] = fmaxf(a, 0.f);
  }
  __syncthreads();
  {
    int o = tid & 127, nb = tid >> 7;  // o fixed; n = nb, nb+2, nb+4, nb+6
    float a0 = p2b[o], a1_ = a0, a2_ = a0, a3_ = a0;
    for (int k4 = 0; k4 < 32; ++k4) {
      float w0 = p2w[(k4 * 4 + 0) * 128 + o];
      float w1 = p2w[(k4 * 4 + 1) * 128 + o];
      float w2 = p2w[(k4 * 4 + 2) * 128 + o];
      float w3 = p2w[(k4 * 4 + 3) * 128 + o];
      float4 v0 = *(const float4*)&t1[nb + 0][k4 * 4];
      float4 v1 = *(const float4*)&t1[nb + 2][k4 * 4];
      float4 v2 = *(const float4*)&t1[nb + 4][k4 * 4];
      float4 v3 = *(const float4*)&t1[nb + 6][k4 * 4];
      a0 += v0.x * w0 + v0.y * w1 + v0.z * w2 + v0.w * w3;
      a1_ += v1.x * w0 + v1.y * w1 + v1.z * w2 + v1.w * w3;
      a2_ += v2.x * w0 + v2.y * w1 + v2.z * w2 + v2.w * w3;
      a3_ += v3.x * w0 + v3.y * w1 + v3.z * w2 + v3.w * w3;
    }
    h_node[(size_t)(n0 + nb + 0) * 128 + o] = f2bf(a0);
    h_node[(size_t)(n0 + nb + 2) * 128 + o] = f2bf(a1_);
    h_node[(size_t)(n0 + nb + 4) * 128 + o] = f2bf(a2_);
    h_node[(size_t)(n0 + nb + 6) * 128 + o] = f2bf(a3_);
  }
}

// ---------------------------------------------------------------------------
// K2: edge MLP (fp32) -> e3T bf16 [128 feat][8192 edges]; also gather h_src
// ---------------------------------------------------------------------------
__global__ void k_edge(const float* __restrict__ ea, const int* __restrict__ eidx,
                       const ushort_t* __restrict__ h_node,
                       const float* __restrict__ e1w, const float* __restrict__ e1b,
                       const float* __restrict__ e2w, const float* __restrict__ e2b,
                       const float* __restrict__ e3w, const float* __restrict__ e3b,
                       ushort_t* __restrict__ e3T, ushort_t* __restrict__ h_src) {
  __shared__ float eas[16][6];
  __shared__ float a1[16][128];
  __shared__ float a2[16][256];
  __shared__ float a3[16][129];
  __shared__ int srcs[16];
  int e0 = blockIdx.x * 16, tid = threadIdx.x;
  if (tid < 80) { int n = tid / 5, j = tid % 5; eas[n][j] = ea[(size_t)(e0 + n) * 5 + j]; }
  if (tid < 16) srcs[tid] = eidx[e0 + tid];
  __syncthreads();
  // gather h_src rows (bf16)
  for (int it = 0; it < 8; ++it) {
    int p = it * 256 + tid;
    int n = p >> 7, o = p & 127;
    h_src[(size_t)(e0 + n) * 128 + o] = h_node[(size_t)srcs[n] * 128 + o];
  }
  // L1: 5 -> 128, relu
  for (int it = 0; it < 8; ++it) {
    int p = it * 256 + tid;
    int n = p >> 7, o = p & 127;
    float a = e1b[o];
#pragma unroll
    for (int j = 0; j < 5; ++j) a += eas[n][j] * e1w[j * 128 + o];
    a1[n][o] = fmaxf(a, 0.f);
  }
  __syncthreads();
  // L2: 128 -> 256, relu. thread o = tid, all 16 edges in registers
  {
    int o = tid;
    float acc[16];
#pragma unroll
    for (int n = 0; n < 16; ++n) acc[n] = e2b[o];
    for (int k4 = 0; k4 < 32; ++k4) {
      float w0 = e2w[(k4 * 4 + 0) * 256 + o];
      float w1 = e2w[(k4 * 4 + 1) * 256 + o];
      float w2 = e2w[(k4 * 4 + 2) * 256 + o];
      float w3 = e2w[(k4 * 4 + 3) * 256 + o];
#pragma unroll
      for (int n = 0; n < 16; ++n) {
        float4 av = *(const float4*)&a1[n][k4 * 4];
        acc[n] += av.x * w0 + av.y * w1 + av.z * w2 + av.w * w3;
      }
    }
#pragma unroll
    for (int n = 0; n < 16; ++n) a2[n][o] = fmaxf(acc[n], 0.f);
  }
  __syncthreads();
  // L3: 256 -> 128, relu. thread: o = tid&127, 8 edges (half)
  {
    int o = tid & 127, nh = tid >> 7;
    float acc[8];
#pragma unroll
    for (int n = 0; n < 8; ++n) acc[n] = e3b[o];
    for (int k4 = 0; k4 < 64; ++k4) {
      float w0 = e3w[(k4 * 4 + 0) * 128 + o];
      float w1 = e3w[(k4 * 4 + 1) * 128 + o];
      float w2 = e3w[(k4 * 4 + 2) * 128 + o];
      float w3 = e3w[(k4 * 4 + 3) * 128 + o];
#pragma unroll
      for (int n = 0; n < 8; ++n) {
        float4 av = *(const float4*)&a2[nh * 8 + n][k4 * 4];
        acc[n] += av.x * w0 + av.y * w1 + av.z * w2 + av.w * w3;
      }
    }
#pragma unroll
    for (int n = 0; n < 8; ++n) a3[nh * 8 + n][o] = fmaxf(acc[n], 0.f);
  }
  __syncthreads();
  // transpose-write: e3T[o][e0..e0+16) as 2x16B per thread
  {
    int o = tid;
    if (o < 128) {
      uint4v q0, q1;
      q0.x = (unsigned)f2bf(a3[0][o]) | ((unsigned)f2bf(a3[1][o]) << 16);
      q0.y = (unsigned)f2bf(a3[2][o]) | ((unsigned)f2bf(a3[3][o]) << 16);
      q0.z = (unsigned)f2bf(a3[4][o]) | ((unsigned)f2bf(a3[5][o]) << 16);
      q0.w = (unsigned)f2bf(a3[6][o]) | ((unsigned)f2bf(a3[7][o]) << 16);
      q1.x = (unsigned)f2bf(a3[8][o]) | ((unsigned)f2bf(a3[9][o]) << 16);
      q1.y = (unsigned)f2bf(a3[10][o]) | ((unsigned)f2bf(a3[11][o]) << 16);
      q1.z = (unsigned)f2bf(a3[12][o]) | ((unsigned)f2bf(a3[13][o]) << 16);
      q1.w = (unsigned)f2bf(a3[14][o]) | ((unsigned)f2bf(a3[15][o]) << 16);
      *(uint4v*)(e3T + (size_t)o * 8192 + e0) = q0;
      *(uint4v*)(e3T + (size_t)o * 8192 + e0 + 8) = q1;
    }
  }
}

// ---------------------------------------------------------------------------
// K3: fused GEMM  partial[s][e][o] = sum over K-tiles in split s of
//     e3[e,t] * (h_src[e,:] @ M_t)   (+ bias tile t=128 with coeff 1)
// BM=128, N=128, BK=128. 512 blocks = 64 mtiles x 8 splits. 256 thr = 4 waves.
// A (h rows) kept in registers for ALL tiles; B double-buffered in LDS.
// LDS layout swizzle: element (r,k) at byte r*256 + (((k>>3)^(r&15))*16) + (k&7)*2
// ---------------------------------------------------------------------------
__launch_bounds__(256, 2)
__global__ void k_gemm(const ushort_t* __restrict__ h_src, const ushort_t* __restrict__ e3T,
                       const ushort_t* __restrict__ e4wT, ushort_t* __restrict__ partial) {
  __shared__ ushort_t bufA[2][16384];  // 2 x 32KB
  __shared__ ushort_t e3s[2048];       // 16 rows x 128 edges, bf16

  int tid = threadIdx.x;
  int w = tid >> 6, ln = tid & 63;
  int g = ln >> 4, l15 = ln & 15;
  int bid = blockIdx.x;
  int mt = bid >> 3, s = bid & 7;
  int e0 = mt * 128;
  int t0 = s * 16;
  int nt = (s == 7) ? 17 : 16;

  // ---- prologue: stage h tile into bufA[0] (swizzled source), e3 rows into e3s
  {
    const ushort_t* hbase = h_src + (size_t)e0 * 128;
    for (int it = 0; it < 8; ++it) {
      int chunk = it * 256 + tid;
      int r = chunk >> 4;
      int Gt = (chunk & 15) ^ (r & 15);
      GL2LDS(hbase + r * 128 + Gt * 8, (char*)&bufA[0][0] + (it * 256 + w * 64) * 16);
    }
    {
      int chunk = tid;
      int tl = chunk >> 4;
      int cc = (chunk & 15) * 8;
      GL2LDS(e3T + (size_t)(t0 + tl) * 8192 + e0 + cc, (char*)&e3s[0] + (w * 64) * 16);
    }
  }
  asm volatile("s_waitcnt vmcnt(0)" ::: "memory");
  __builtin_amdgcn_s_barrier();
  asm volatile("" ::: "memory");

  // ---- A fragments (reused across ALL K-tiles): afr[rf][ks]
  short8 afr[2][4];
#pragma unroll
  for (int rf = 0; rf < 2; ++rf)
#pragma unroll
    for (int ks = 0; ks < 4; ++ks) {
      int row = w * 32 + rf * 16 + l15;
      int gr = (ks * 4 + g) ^ (row & 15);
      afr[rf][ks] = *(const short8*)((const char*)&bufA[0][0] + row * 256 + gr * 16);
    }
  asm volatile("s_waitcnt lgkmcnt(0)" ::: "memory");
  __builtin_amdgcn_s_barrier();
  asm volatile("" ::: "memory");

  auto stageB = [&](int b, int tg) {
    const ushort_t* wbase = e4wT + (size_t)tg * 128;
    for (int it = 0; it < 8; ++it) {
      int chunk = it * 256 + tid;
      int r = chunk >> 4;
      int Gt = (chunk & 15) ^ (r & 15);
      GL2LDS(wbase + (size_t)r * 16512 + Gt * 8, (char*)&bufA[b][0] + (it * 256 + w * 64) * 16);
    }
  };
  stageB(0, t0);
  stageB(1, t0 + 1);

  float acc[2][8][4];
#pragma unroll
  for (int rf = 0; rf < 2; ++rf)
#pragma unroll
    for (int cf = 0; cf < 8; ++cf)
#pragma unroll
      for (int r2 = 0; r2 < 4; ++r2) acc[rf][cf][r2] = 0.f;

  const f32x4 zero4 = {0.f, 0.f, 0.f, 0.f};

  for (int tl = 0; tl < nt; ++tl) {
    if (tl + 1 < nt) { asm volatile("s_waitcnt vmcnt(8)" ::: "memory"); }
    else             { asm volatile("s_waitcnt vmcnt(0)" ::: "memory"); }
    __builtin_amdgcn_s_barrier();
    asm volatile("" ::: "memory");
    int cur = tl & 1;
    int tg = t0 + tl;

    float sc[2][4];
    if (tg < 128) {
#pragma unroll
      for (int rf = 0; rf < 2; ++rf) {
        int row = w * 32 + rf * 16 + g * 4;
        short4v ev = *(const short4v*)((const char*)&e3s[0] + tl * 256 + row * 2);
#pragma unroll
        for (int r2 = 0; r2 < 4; ++r2) sc[rf][r2] = bf2f((ushort_t)ev[r2]);
      }
    } else {
#pragma unroll
      for (int rf = 0; rf < 2; ++rf)
#pragma unroll
        for (int r2 = 0; r2 < 4; ++r2) sc[rf][r2] = 1.f;
    }

    f32x4 part[2][8];
#pragma unroll
    for (int ks = 0; ks < 4; ++ks) {
#pragma unroll
      for (int ch = 0; ch < 2; ++ch) {
        short8 bfr[4];
#pragma unroll
        for (int cc = 0; cc < 4; ++cc) {
          int cf = ch * 4 + cc;
          int nrow = cf * 16 + l15;
          int gr = (ks * 4 + g) ^ (nrow & 15);
          bfr[cc] = *(const short8*)((const char*)&bufA[cur][0] + nrow * 256 + gr * 16);
        }
#pragma unroll
        for (int rf = 0; rf < 2; ++rf)
#pragma unroll
          for (int cc = 0; cc < 4; ++cc) {
            int cf = ch * 4 + cc;
            if (ks == 0)
              part[rf][cf] = __builtin_amdgcn_mfma_f32_16x16x32_bf16(afr[rf][0], bfr[cc], zero4, 0, 0, 0);
            else
              part[rf][cf] = __builtin_amdgcn_mfma_f32_16x16x32_bf16(afr[rf][ks], bfr[cc], part[rf][cf], 0, 0, 0);
          }
      }
    }
#pragma unroll
    for (int rf = 0; rf < 2; ++rf)
#pragma unroll
      for (int cf = 0; cf < 8; ++cf)
#pragma unroll
        for (int r2 = 0; r2 < 4; ++r2) acc[rf][cf][r2] += sc[rf][r2] * part[rf][cf][r2];

    asm volatile("s_waitcnt lgkmcnt(0)" ::: "memory");
    __builtin_amdgcn_s_barrier();
    asm volatile("" ::: "memory");
    if (tl + 2 < nt) stageB(cur, t0 + tl + 2);
  }

  // epilogue: partial[s][e0+row][col] (bf16)
#pragma unroll
  for (int rf = 0; rf < 2; ++rf)
#pragma unroll
    for (int cf = 0; cf < 8; ++cf)
#pragma unroll
      for (int r2 = 0; r2 < 4; ++r2) {
        int row = w * 32 + rf * 16 + g * 4 + r2;
        int col = cf * 16 + l15;
        partial[((size_t)s * 8192 + e0 + row) * 128 + col] = f2bf(acc[rf][cf][r2]);
      }
}

// ---------------------------------------------------------------------------
// K4: reduce split partials + scatter-add into agg[dst], count edges per node
// ---------------------------------------------------------------------------
__global__ void k_reduce(const ushort_t* __restrict__ partial, const int* __restrict__ eidx,
                         float* __restrict__ agg, float* __restrict__ cnt) {
  int id = blockIdx.x * 256 + threadIdx.x;
  int e = id >> 7, o = id & 127;
  float v = 0.f;
#pragma unroll
  for (int s2 = 0; s2 < 8; ++s2) v += bf2f(partial[((size_t)s2 * 8192 + e) * 128 + o]);
  int d = eidx[8192 + e];
  atomicAdd(&agg[(size_t)d * 128 + o], v);
  if (o == 0) atomicAdd(&cnt[d], 1.0f);
}

// ---------------------------------------------------------------------------
// K5: per-graph pooling of agg/max(cnt,1), batch is sorted
// ---------------------------------------------------------------------------
__device__ __forceinline__ int lbound(const int* a, int n, int v) {
  int lo = 0, hi = n;
  while (lo < hi) { int m = (lo + hi) >> 1; if (a[m] < v) lo = m + 1; else hi = m; }
  return lo;
}

__global__ void k_pool(const float* __restrict__ agg, const float* __restrict__ cnt,
                       const int* __restrict__ batch, float* __restrict__ out) {
  int gph = blockIdx.x, o = threadIdx.x;
  int lo = lbound(batch, 4096, gph);
  int hi = lbound(batch, 4096, gph + 1);
  float a = 0.f;
  for (int n = lo; n < hi; ++n) a += agg[(size_t)n * 128 + o] / fmaxf(cnt[n], 1.0f);
  out[(size_t)gph * 128 + o] = a;
}

// ---------------------------------------------------------------------------
extern "C" void kernel_launch(void* const* d_in, const int* in_sizes, int n_in,
                              void* d_out, int out_size, void* d_ws, size_t ws_size,
                              hipStream_t stream) {
  (void)in_sizes; (void)n_in; (void)out_size; (void)ws_size;
  const float* x   = (const float*)d_in[0];
  const float* ea  = (const float*)d_in[1];
  const int*   ei  = (const int*)d_in[2];
  const int*   bat = (const int*)d_in[3];
  const float* p1w = (const float*)d_in[4];  const float* p1b = (const float*)d_in[5];
  const float* p2w = (const float*)d_in[6];  const float* p2b = (const float*)d_in[7];
  const float* e1w = (const float*)d_in[8];  const float* e1b = (const float*)d_in[9];
  const float* e2w = (const float*)d_in[10]; const float* e2b = (const float*)d_in[11];
  const float* e3w = (const float*)d_in[12]; const float* e3b = (const float*)d_in[13];
  const float* e4w = (const float*)d_in[14]; const float* e4b = (const float*)d_in[15];

  char* ws = (char*)d_ws;
  ushort_t* e4wT   = (ushort_t*)(ws + 0);         // 128 x 16512 bf16 = 4,227,072
  ushort_t* h_node = (ushort_t*)(ws + 4227072);   // 4096 x 128 bf16 = 1,048,576
  ushort_t* h_srcp = (ushort_t*)(ws + 5275648);   // 8192 x 128 bf16 = 2,097,152
  ushort_t* e3T    = (ushort_t*)(ws + 7372800);   // 128 x 8192 bf16 = 2,097,152
  ushort_t* part   = (ushort_t*)(ws + 9469952);   // 8 x 8192 x 128 bf16 = 16,777,216
  float*    agg    = (float*)(ws + 26247168);     // 4096 x 128 f32 = 2,097,152
  float*    cnt    = (float*)(ws + 28344320);     // 4096 f32 = 16,384

  hipMemsetAsync(ws + 26247168, 0, 2097152 + 16384, stream);

  k_prep  <<<258,  256, 0, stream>>>(e4w, e4b, e4wT);
  k_node  <<<512,  256, 0, stream>>>(x, p1w, p1b, p2w, p2b, h_node);
  k_edge  <<<512,  256, 0, stream>>>(ea, ei, h_node, e1w, e1b, e2w, e2b, e3w, e3b, e3T, h_srcp);
  k_gemm  <<<512,  256, 0, stream>>>(h_srcp, e3T, e4wT, part);
  k_reduce<<<4096, 256, 0, stream>>>(part, ei, agg, cnt);
  k_pool  <<<64,   128, 0, stream>>>(agg, cnt, bat, (float*)d_out);
}